// Round 9
// baseline (400.401 us; speedup 1.0000x reference)
//
#include <hip/hip_runtime.h>
#include <hip/hip_cooperative_groups.h>
#include <math.h>

namespace cg = cooperative_groups;

#define D 8192
#define B 8
#define E 131072
#define HID 256
#define TDIM 128
#define MAXDEG 64
#define NBLK 512

// ws float-index layout
#define OFF_XT 0
#define OFF_DD 65536
#define OFF_UU 131072
#define OFF_Y0 196608
#define OFF_Y1 262144
#define OFF_G  327680   // 2048
#define OFF_SC 329728   // 16
#define OFF_P1 329744   // 8192  tmlp layer1 partials [8][4][256]
#define OFF_H1 337936   // 2048
#define OFF_P2 339984   // 8192  tmlp layer2 partials [8][4][256]
#define OFF_PS 348176   // 16384 out-mlp partials [8][8][256]
// ws int-index layout ((int*)ws)
#define IOFF_CNT  364560   // 16384 ints
#define IOFF_EDGE 380944   // int2[2*8192*64] = 2,097,152 ints (8B aligned: even)

__global__ __launch_bounds__(256) void k_mega(
        const float* __restrict__ x, const float* __restrict__ t,
        const int* __restrict__ ldi, const float* __restrict__ ldv,
        const int* __restrict__ lui, const float* __restrict__ luv,
        const float* __restrict__ W1, const float* __restrict__ W2,
        const float* __restrict__ t_w1, const float* __restrict__ t_b1,
        const float* __restrict__ t_w2, const float* __restrict__ t_b2,
        const float* __restrict__ map_w, const float* __restrict__ map_b,
        const float* __restrict__ o_w1, const float* __restrict__ o_b1,
        const float* __restrict__ o_w2, const float* __restrict__ o_b2,
        float* __restrict__ ws, float* __restrict__ out)
{
    cg::grid_group grid = cg::this_grid();
    const int blk = blockIdx.x, tid = threadIdx.x;
    __shared__ float smem[1024];

    // ---------- P0: prep (blk 0-63) | tmlp layer1 partials (blk 64-95) | 9 scalars (blk 96)
    if (blk < 64) {
        #pragma unroll
        for (int it = 0; it < 4; it++) {
            int idx = blk * 1024 + it * 256 + tid;        // 0..65535
            ws[OFF_XT + idx] = x[(idx & 7) * D + (idx >> 3)];
            out[idx] = o_b2[idx & (D - 1)];
            if (idx < 16384) ((int*)ws)[IOFF_CNT + idx] = 0;
        }
    } else if (blk < 96) {
        int b = (blk - 64) >> 2, ic = (blk - 64) & 3;
        if (tid < TDIM) {
            int jj = tid & 63;
            float freq = expf(-0.14391156831212787f * (float)jj);  // ln(10000)/64
            float a = t[b] * freq;
            smem[tid] = (tid < 64) ? cosf(a) : sinf(a);
        }
        __syncthreads();
        float z = 0.f;
        #pragma unroll 8
        for (int i = ic * 32; i < ic * 32 + 32; i++) z += smem[i] * t_w1[i * HID + tid];
        ws[OFF_P1 + (b * 4 + ic) * HID + tid] = z;
    } else if (blk == 96) {
        int w = tid >> 6, lane = tid & 63;
        for (int jk = w; jk < 9; jk += 4) {
            int jj = jk / 3, k = jk % 3;
            float acc = 0.f;
            #pragma unroll
            for (int q = 0; q < 4; q++) {
                int i = lane + 64 * q;
                acc += W1[i * 3 + k] * W2[i * 3 + jj];
            }
            #pragma unroll
            for (int off = 32; off > 0; off >>= 1) acc += __shfl_down(acc, off, 64);
            if (lane == 0) ws[OFF_SC + jj * 3 + k] = acc;
        }
    }
    grid.sync();

    // ---------- P1: bucket fill (all blocks, 2 edges/thread) | h1 silu (blk 64-71)
    {
        int t0 = blk * 256 + tid;                          // 0..131071
        #pragma unroll
        for (int it = 0; it < 2; it++) {
            int te = t0 + it * 131072;                     // 0..262143
            int m = te >> 17, e = te & (E - 1);
            const int* idx = m ? lui : ldi;
            const float* val = m ? luv : ldv;
            int row = idx[e], col = idx[E + e];
            float v = val[e];
            int bucket = m * D + row;
            int slot = atomicAdd((int*)ws + IOFF_CNT + bucket, 1);
            ((int2*)((int*)ws + IOFF_EDGE))[bucket * MAXDEG + slot] =
                make_int2(col, __float_as_int(v));
        }
    }
    if (blk >= 64 && blk < 72) {
        int b = blk - 64;
        float zz = t_b1[tid]
                 + ws[OFF_P1 + (b * 4 + 0) * HID + tid] + ws[OFF_P1 + (b * 4 + 1) * HID + tid]
                 + ws[OFF_P1 + (b * 4 + 2) * HID + tid] + ws[OFF_P1 + (b * 4 + 3) * HID + tid];
        ws[OFF_H1 + b * HID + tid] = zz / (1.f + expf(-zz));
    }
    grid.sync();

    // ---------- P2: spmv1 wave-per-bucket (all) | tmlp layer2 partials (blk 64-95)
    {
        int gwid = (blk * 256 + tid) >> 6;                 // 0..2047
        int lane = tid & 63, slot = lane >> 3, b = lane & 7;
        for (int wid = gwid; wid < 16384; wid += 2048) {
            int m = wid >> 13, r = wid & (D - 1);
            int deg = ((const int*)ws)[IOFF_CNT + wid];
            const int2* ep = (const int2*)((const int*)ws + IOFF_EDGE) + wid * MAXDEG;
            float acc = 0.f;
            for (int p = slot; p < deg; p += 8) {
                int2 ed = ep[p];
                acc += __int_as_float(ed.y) * ws[OFF_XT + ed.x * 8 + b];
            }
            acc += __shfl_xor(acc, 8, 64);
            acc += __shfl_xor(acc, 16, 64);
            acc += __shfl_xor(acc, 32, 64);
            if (lane < 8) ws[(m ? OFF_UU : OFF_DD) + r * 8 + lane] = acc;
        }
    }
    if (blk >= 64 && blk < 96) {
        int b = (blk - 64) >> 2, ic = (blk - 64) & 3;
        float z = 0.f;
        #pragma unroll 8
        for (int i = ic * 64; i < ic * 64 + 64; i++)
            z += ws[OFF_H1 + b * HID + i] * t_w2[i * HID + tid];
        ws[OFF_P2 + (b * 4 + ic) * HID + tid] = z;
    }
    grid.sync();

    // ---------- P3: spmv2 (all) | g-init (blk 64-71)
    {
        const float* sc = ws + OFF_SC;
        int gwid = (blk * 256 + tid) >> 6;
        int lane = tid & 63, slot = lane >> 3, b = lane & 7;
        for (int wid = gwid; wid < 16384; wid += 2048) {
            int m = wid >> 13, r = wid & (D - 1);
            int deg = ((const int*)ws)[IOFF_CNT + wid];
            const int2* ep = (const int2*)((const int*)ws + IOFF_EDGE) + wid * MAXDEG;
            float c0, c1, c2;
            if (m == 0) { c0 = sc[3]; c1 = sc[4]; c2 = sc[5]; }
            else        { c0 = sc[6]; c1 = sc[7]; c2 = sc[8]; }
            float acc = 0.f;
            for (int p = slot; p < deg; p += 8) {
                int2 ed = ep[p];
                int ci = ed.x * 8 + b;
                float h = c0 * ws[OFF_XT + ci] + c1 * ws[OFF_DD + ci] + c2 * ws[OFF_UU + ci];
                acc += __int_as_float(ed.y) * h;
            }
            acc += __shfl_xor(acc, 8, 64);
            acc += __shfl_xor(acc, 16, 64);
            acc += __shfl_xor(acc, 32, 64);
            if (lane < 8) {
                int i = r * 8 + lane;
                if (m == 0) {
                    acc += sc[0] * ws[OFF_XT + i] + sc[1] * ws[OFF_DD + i] + sc[2] * ws[OFF_UU + i];
                    ws[OFF_Y0 + i] = acc;
                } else {
                    ws[OFF_Y1 + i] = acc;
                }
            }
        }
    }
    if (blk >= 64 && blk < 72) {
        int b = blk - 64;
        ws[OFF_G + b * HID + tid] = map_b[tid] + t_b2[tid]
                 + ws[OFF_P2 + (b * 4 + 0) * HID + tid] + ws[OFF_P2 + (b * 4 + 1) * HID + tid]
                 + ws[OFF_P2 + (b * 4 + 2) * HID + tid] + ws[OFF_P2 + (b * 4 + 3) * HID + tid];
    }
    grid.sync();

    // ---------- P4: map  g[b,j] += sum_n (y0+y1)[n,b]*map_w[n,j]  (blk 0-255, 32 rows)
    if (blk < 256) {
        int base = blk * 256;
        smem[tid] = ws[OFF_Y0 + base + tid] + ws[OFF_Y1 + base + tid];
        __syncthreads();
        float acc[8] = {0.f, 0.f, 0.f, 0.f, 0.f, 0.f, 0.f, 0.f};
        int nbase = blk * 32;
        #pragma unroll 4
        for (int r = 0; r < 32; r++) {
            float w = map_w[(nbase + r) * HID + tid];
            #pragma unroll
            for (int b = 0; b < 8; b++) acc[b] += smem[r * 8 + b] * w;
        }
        #pragma unroll
        for (int b = 0; b < 8; b++) atomicAdd(&ws[OFF_G + b * HID + tid], acc[b]);
    }
    grid.sync();

    // ---------- P5: out-mlp partials  part_s[b][ic][j] = sum_{i in ic*32..} g[b,i]*o_w1[i,j]
    if (blk < 64) {
        int b = blk >> 3, ic = blk & 7;
        float z = 0.f;
        #pragma unroll 8
        for (int i = ic * 32; i < ic * 32 + 32; i++)
            z += ws[OFF_G + b * HID + i] * o_w1[i * HID + tid];
        ws[OFF_PS + (b * 8 + ic) * HID + tid] = z;
    }
    grid.sync();

    // ---------- P7: out  (blk 0-127: nc=blk&31, jc=blk>>5)
    if (blk < 128) {
        int nc = blk & 31, jc = blk >> 5;
        for (int i = tid; i < 512; i += 256) {
            int b = i >> 6, jj = i & 63, j = jc * 64 + jj;
            float z = o_b1[j];
            #pragma unroll
            for (int ic = 0; ic < 8; ic++) z += ws[OFF_PS + (b * 8 + ic) * HID + j];
            smem[i] = z / (1.f + expf(-z));
        }
        __syncthreads();
        int n = nc * 256 + tid;
        float acc[8] = {0.f, 0.f, 0.f, 0.f, 0.f, 0.f, 0.f, 0.f};
        #pragma unroll 4
        for (int jj = 0; jj < 64; jj++) {
            int j = jc * 64 + jj;
            float w = o_w2[j * D + n];
            #pragma unroll
            for (int b = 0; b < 8; b++) acc[b] += smem[b * 64 + jj] * w;
        }
        #pragma unroll
        for (int b = 0; b < 8; b++) atomicAdd(&out[b * D + n], acc[b]);
    }
}

extern "C" void kernel_launch(void* const* d_in, const int* in_sizes, int n_in,
                              void* d_out, int out_size, void* d_ws, size_t ws_size,
                              hipStream_t stream)
{
    const float* x     = (const float*)d_in[0];
    const float* t     = (const float*)d_in[1];
    const int*   ldi   = (const int*)  d_in[2];
    const float* ldv   = (const float*)d_in[3];
    const int*   lui   = (const int*)  d_in[4];
    const float* luv   = (const float*)d_in[5];
    const float* W1    = (const float*)d_in[6];
    const float* W2    = (const float*)d_in[7];
    const float* t_w1  = (const float*)d_in[8];
    const float* t_b1  = (const float*)d_in[9];
    const float* t_w2  = (const float*)d_in[10];
    const float* t_b2  = (const float*)d_in[11];
    const float* map_w = (const float*)d_in[12];
    const float* map_b = (const float*)d_in[13];
    const float* o_w1  = (const float*)d_in[14];
    const float* o_b1  = (const float*)d_in[15];
    const float* o_w2  = (const float*)d_in[16];
    const float* o_b2  = (const float*)d_in[17];
    float* out = (float*)d_out;
    float* ws  = (float*)d_ws;

    void* args[] = {
        (void*)&x, (void*)&t, (void*)&ldi, (void*)&ldv, (void*)&lui, (void*)&luv,
        (void*)&W1, (void*)&W2, (void*)&t_w1, (void*)&t_b1, (void*)&t_w2, (void*)&t_b2,
        (void*)&map_w, (void*)&map_b, (void*)&o_w1, (void*)&o_b1, (void*)&o_w2, (void*)&o_b2,
        (void*)&ws, (void*)&out
    };
    hipLaunchCooperativeKernel((const void*)k_mega, dim3(NBLK), dim3(256), args, 0, stream);
}

// Round 10
// 68.105 us; speedup vs baseline: 5.8792x; 5.8792x over previous
//
#include <hip/hip_runtime.h>
#include <math.h>

#define D 8192
#define B 8
#define E 131072
#define HID 256
#define TDIM 128

// ws float-index layout
#define OFF_XDU 0        // [8192][3][8]: x,d,u planes interleaved -> 196608
#define OFF_Y   196608   // [8192][8] -> 65536
#define OFF_G   262144   // 2048
#define OFF_S   264192   // 2048
#define OFF_SC  266240   // 16

// blocks 0..63  : XDU init (x transpose, d=u=0), Y=0, out = o_b2
// blocks 64..71 : per-batch time-embedding MLP -> g = map_b + t_out
// block  72     : 9 collapsed scalars sc[j*3+k] = sum_i W1[0,i,k]*W2[i,0,j]
__global__ __launch_bounds__(1024) void k_front(
        const float* __restrict__ x, const float* __restrict__ t,
        const float* __restrict__ W1, const float* __restrict__ W2,
        const float* __restrict__ t_w1, const float* __restrict__ t_b1,
        const float* __restrict__ t_w2, const float* __restrict__ t_b2,
        const float* __restrict__ map_b, const float* __restrict__ o_b2,
        float* __restrict__ ws, float* __restrict__ out)
{
    const int blk = blockIdx.x, tid = threadIdx.x;
    if (blk < 64) {
        int idx = blk * 1024 + tid;               // 0..65535
        int b = idx & 7, n = idx >> 3;
        ws[OFF_XDU + n * 24 + b]      = x[b * D + n];
        ws[OFF_XDU + n * 24 + 8 + b]  = 0.f;
        ws[OFF_XDU + n * 24 + 16 + b] = 0.f;
        ws[OFF_Y + idx] = 0.f;
        out[idx] = o_b2[idx & (D - 1)];           // idx = b*D + n
        return;
    }
    if (blk < 72) {
        const int b = blk - 64;
        __shared__ float emb[TDIM];
        __shared__ float h1[HID];
        __shared__ float part[4][HID];
        float tb = t[b];
        if (tid < TDIM) {
            int j = tid & 63;
            float freq = expf(-0.14391156831212787f * (float)j); // ln(10000)/64
            float a = tb * freq;
            emb[tid] = (tid < 64) ? cosf(a) : sinf(a);
        }
        __syncthreads();
        const int j = tid & 255, ic = tid >> 8;   // ic in 0..3
        float z = 0.f;
        #pragma unroll 8
        for (int i = ic * 32; i < ic * 32 + 32; i++) z += emb[i] * t_w1[i * HID + j];
        part[ic][j] = z;
        __syncthreads();
        if (tid < HID) {
            float zz = t_b1[tid] + part[0][tid] + part[1][tid] + part[2][tid] + part[3][tid];
            h1[tid] = zz / (1.f + expf(-zz));
        }
        __syncthreads();
        float z2 = 0.f;
        #pragma unroll 8
        for (int i = ic * 64; i < ic * 64 + 64; i++) z2 += h1[i] * t_w2[i * HID + j];
        part[ic][j] = z2;
        __syncthreads();
        if (tid < HID) {
            float zz = t_b2[tid] + part[0][tid] + part[1][tid] + part[2][tid] + part[3][tid];
            (ws + OFF_G)[b * HID + tid] = map_b[tid] + zz;
        }
        return;
    }
    // block 72: 9 scalars via per-wave shuffle reduction (waves 0..8)
    {
        int w = tid >> 6, lane = tid & 63;
        if (w < 9) {
            int jj = w / 3, k = w % 3;
            float acc = 0.f;
            #pragma unroll
            for (int q = 0; q < 4; q++) {
                int i = lane + 64 * q;
                acc += W1[i * 3 + k] * W2[i * 3 + jj];
            }
            #pragma unroll
            for (int off = 32; off > 0; off >>= 1) acc += __shfl_down(acc, off, 64);
            if (lane == 0) (ws + OFF_SC)[jj * 3 + k] = acc;
        }
    }
}

// pass 1: XDU[row].d += v * XDU[col].x  (m=0) ; XDU[row].u += v * XDU[col].x (m=1)
__global__ void k_scat1(const int* __restrict__ ldi, const float* __restrict__ ldv,
                        const int* __restrict__ lui, const float* __restrict__ luv,
                        float* __restrict__ ws)
{
    int gtid = blockIdx.x * 256 + threadIdx.x;    // 0 .. 2*E*8-1
    int b = gtid & 7;
    int e = gtid >> 3;
    int plane;
    const int* idx; const float* val;
    if (e < E) { idx = ldi; val = ldv; plane = 8; }
    else       { e -= E; idx = lui; val = luv; plane = 16; }
    int row = idx[e];
    int col = idx[E + e];
    float v = val[e];
    atomicAdd(&ws[OFF_XDU + row * 24 + plane + b], v * ws[OFF_XDU + col * 24 + b]);
}

// pass 2: Y[row,b] += v * h(col,b), h = c0 x + c1 d + c2 u (contiguous 96B read)
__global__ void k_scat2(const int* __restrict__ ldi, const float* __restrict__ ldv,
                        const int* __restrict__ lui, const float* __restrict__ luv,
                        float* __restrict__ ws)
{
    int gtid = blockIdx.x * 256 + threadIdx.x;    // 0 .. 2*E*8-1
    int b = gtid & 7;
    int e = gtid >> 3;
    const float* sc = ws + OFF_SC;
    const int* idx; const float* val; float c0, c1, c2;
    if (e < E) { idx = ldi; val = ldv; c0 = sc[3]; c1 = sc[4]; c2 = sc[5]; }
    else       { e -= E; idx = lui; val = luv; c0 = sc[6]; c1 = sc[7]; c2 = sc[8]; }
    int row = idx[e];
    int col = idx[E + e];
    float v = val[e];
    const float* p = ws + OFF_XDU + col * 24 + b;
    float h = c0 * p[0] + c1 * p[8] + c2 * p[16];
    atomicAdd(&ws[OFF_Y + row * 8 + b], v * h);
}

// g[b,j] += sum_n yfull[n,b] * map_w[n,j], yfull = a0 x + a1 d + a2 u + Y
// 256 blocks x 32 rows each (all CUs busy, serial depth 32)
__global__ void k_map(const float* __restrict__ map_w, float* __restrict__ ws)
{
    __shared__ float yf[32 * 8];
    int blk = blockIdx.x, tid = threadIdx.x;
    const float* sc = ws + OFF_SC;
    float* g = ws + OFF_G;
    int nbase = blk * 32;
    {
        int r = tid >> 3, b = tid & 7;
        const float* p = ws + OFF_XDU + (nbase + r) * 24 + b;
        yf[tid] = sc[0] * p[0] + sc[1] * p[8] + sc[2] * p[16]
                + ws[OFF_Y + (nbase + r) * 8 + b];
    }
    __syncthreads();
    float acc[8] = {0.f, 0.f, 0.f, 0.f, 0.f, 0.f, 0.f, 0.f};
    #pragma unroll 4
    for (int r = 0; r < 32; r++) {
        float w = map_w[(nbase + r) * HID + tid];
        #pragma unroll
        for (int b = 0; b < 8; b++) acc[b] += yf[r * 8 + b] * w;
    }
    #pragma unroll
    for (int b = 0; b < 8; b++) atomicAdd(&g[b * HID + tid], acc[b]);
}

// s[b,j] = silu(sum_i g[b,i]*o_w1[i,j] + o_b1[j])  (8 blocks x 1024 thr, 4-way split)
__global__ __launch_bounds__(1024) void k_mlp(const float* __restrict__ o_w1,
                                              const float* __restrict__ o_b1,
                                              float* __restrict__ ws)
{
    __shared__ float gs[HID];
    __shared__ float part[4][HID];
    int b = blockIdx.x, tid = threadIdx.x;
    if (tid < HID) gs[tid] = (ws + OFF_G)[b * HID + tid];
    __syncthreads();
    int j = tid & 255, ic = tid >> 8;
    float z = 0.f;
    #pragma unroll 8
    for (int i = ic * 64; i < ic * 64 + 64; i++) z += gs[i] * o_w1[i * HID + j];
    part[ic][j] = z;
    __syncthreads();
    if (tid < HID) {
        float zz = o_b1[tid] + part[0][tid] + part[1][tid] + part[2][tid] + part[3][tid];
        (ws + OFF_S)[b * HID + tid] = zz / (1.f + expf(-zz));
    }
}

// out[b,n] += sum_j s[b,j]*o_w2[j,n]  (grid 32 nc x 8 jc, 32 j per jc; out pre-biased)
__global__ void k_out(const float* __restrict__ o_w2, const float* __restrict__ ws,
                      float* __restrict__ out)
{
    __shared__ float ssl[8 * 32];
    int nc = blockIdx.x, jc = blockIdx.y, tid = threadIdx.x;
    const float* s = ws + OFF_S;
    if (tid < 256) {
        int b = tid >> 5, jj = tid & 31;
        ssl[tid] = s[b * HID + jc * 32 + jj];
    }
    __syncthreads();
    int n = nc * 256 + tid;
    float acc[8] = {0.f, 0.f, 0.f, 0.f, 0.f, 0.f, 0.f, 0.f};
    #pragma unroll 4
    for (int jj = 0; jj < 32; jj++) {
        int j = jc * 32 + jj;
        float w = o_w2[j * D + n];
        #pragma unroll
        for (int b = 0; b < 8; b++) acc[b] += ssl[b * 32 + jj] * w;
    }
    #pragma unroll
    for (int b = 0; b < 8; b++) atomicAdd(&out[b * D + n], acc[b]);
}

extern "C" void kernel_launch(void* const* d_in, const int* in_sizes, int n_in,
                              void* d_out, int out_size, void* d_ws, size_t ws_size,
                              hipStream_t stream)
{
    const float* x     = (const float*)d_in[0];
    const float* t     = (const float*)d_in[1];
    const int*   ldi   = (const int*)  d_in[2];
    const float* ldv   = (const float*)d_in[3];
    const int*   lui   = (const int*)  d_in[4];
    const float* luv   = (const float*)d_in[5];
    const float* W1    = (const float*)d_in[6];
    const float* W2    = (const float*)d_in[7];
    const float* t_w1  = (const float*)d_in[8];
    const float* t_b1  = (const float*)d_in[9];
    const float* t_w2  = (const float*)d_in[10];
    const float* t_b2  = (const float*)d_in[11];
    const float* map_w = (const float*)d_in[12];
    const float* map_b = (const float*)d_in[13];
    const float* o_w1  = (const float*)d_in[14];
    const float* o_b1  = (const float*)d_in[15];
    const float* o_w2  = (const float*)d_in[16];
    const float* o_b2  = (const float*)d_in[17];
    float* out = (float*)d_out;
    float* ws  = (float*)d_ws;

    k_front<<<73, 1024, 0, stream>>>(x, t, W1, W2, t_w1, t_b1, t_w2, t_b2,
                                     map_b, o_b2, ws, out);
    k_scat1<<<2 * E * 8 / 256, 256, 0, stream>>>(ldi, ldv, lui, luv, ws);
    k_scat2<<<2 * E * 8 / 256, 256, 0, stream>>>(ldi, ldv, lui, luv, ws);
    k_map<<<256, 256, 0, stream>>>(map_w, ws);
    k_mlp<<<8, 1024, 0, stream>>>(o_w1, o_b1, ws);
    k_out<<<dim3(32, 8), 256, 0, stream>>>(o_w2, ws, out);
}

// Round 11
// 67.269 us; speedup vs baseline: 5.9522x; 1.0124x over previous
//
#include <hip/hip_runtime.h>
#include <math.h>

#define D 8192
#define B 8
#define E 131072
#define HID 256
#define TDIM 128

// ws float-index layout (planar, R4-proven)
#define OFF_XT 0
#define OFF_DD 65536
#define OFF_UU 131072
#define OFF_Y  196608
#define OFF_G  262144   // 2048
#define OFF_SC 264192   // 16

// blocks 0..63  : prep (xT transpose, dd=uu=y=0)
// blocks 64..71 : per-batch time-embedding MLP -> g = map_b + t_out
// block  72     : 9 collapsed scalars sc[j*3+k] = sum_i W1[0,i,k]*W2[i,0,j]
__global__ __launch_bounds__(1024) void k_front(
        const float* __restrict__ x, const float* __restrict__ t,
        const float* __restrict__ W1, const float* __restrict__ W2,
        const float* __restrict__ t_w1, const float* __restrict__ t_b1,
        const float* __restrict__ t_w2, const float* __restrict__ t_b2,
        const float* __restrict__ map_b, float* __restrict__ ws)
{
    const int blk = blockIdx.x, tid = threadIdx.x;
    if (blk < 64) {
        int idx = blk * 1024 + tid;               // 0..65535
        ws[OFF_XT + idx] = x[(idx & 7) * D + (idx >> 3)];
        ws[OFF_DD + idx] = 0.f;
        ws[OFF_UU + idx] = 0.f;
        ws[OFF_Y  + idx] = 0.f;
        return;
    }
    if (blk < 72) {
        const int b = blk - 64;
        __shared__ float emb[TDIM];
        __shared__ float h1[HID];
        __shared__ float part[4][HID];
        float tb = t[b];
        if (tid < TDIM) {
            int j = tid & 63;
            float freq = expf(-0.14391156831212787f * (float)j); // ln(10000)/64
            float a = tb * freq;
            emb[tid] = (tid < 64) ? cosf(a) : sinf(a);
        }
        __syncthreads();
        const int j = tid & 255, ic = tid >> 8;   // ic in 0..3
        float z = 0.f;
        #pragma unroll 8
        for (int i = ic * 32; i < ic * 32 + 32; i++) z += emb[i] * t_w1[i * HID + j];
        part[ic][j] = z;
        __syncthreads();
        if (tid < HID) {
            float zz = t_b1[tid] + part[0][tid] + part[1][tid] + part[2][tid] + part[3][tid];
            h1[tid] = zz / (1.f + expf(-zz));
        }
        __syncthreads();
        float z2 = 0.f;
        #pragma unroll 8
        for (int i = ic * 64; i < ic * 64 + 64; i++) z2 += h1[i] * t_w2[i * HID + j];
        part[ic][j] = z2;
        __syncthreads();
        if (tid < HID) {
            float zz = t_b2[tid] + part[0][tid] + part[1][tid] + part[2][tid] + part[3][tid];
            (ws + OFF_G)[b * HID + tid] = map_b[tid] + zz;
        }
        return;
    }
    // block 72: 9 scalars via per-wave shuffle reduction (waves 0..8)
    {
        int w = tid >> 6, lane = tid & 63;
        if (w < 9) {
            int jj = w / 3, k = w % 3;
            float acc = 0.f;
            #pragma unroll
            for (int q = 0; q < 4; q++) {
                int i = lane + 64 * q;
                acc += W1[i * 3 + k] * W2[i * 3 + jj];
            }
            #pragma unroll
            for (int off = 32; off > 0; off >>= 1) acc += __shfl_down(acc, off, 64);
            if (lane == 0) (ws + OFF_SC)[jj * 3 + k] = acc;
        }
    }
}

// pass 1: dd[row,b] += v * xT[col,b] (m=0) ; uu[row,b] += v * xT[col,b] (m=1)
__global__ void k_scat1(const int* __restrict__ ldi, const float* __restrict__ ldv,
                        const int* __restrict__ lui, const float* __restrict__ luv,
                        float* __restrict__ ws)
{
    int gtid = blockIdx.x * 256 + threadIdx.x;    // 0 .. 2*E*8-1
    int b = gtid & 7;
    int e = gtid >> 3;
    const int* idx; const float* val; float* dst;
    if (e < E) { idx = ldi; val = ldv; dst = ws + OFF_DD; }
    else       { e -= E; idx = lui; val = luv; dst = ws + OFF_UU; }
    int row = idx[e];
    int col = idx[E + e];
    float v = val[e];
    atomicAdd(&dst[row * 8 + b], v * ws[OFF_XT + col * 8 + b]);
}

// pass 2: Y[row,b] += v * h(col,b), h = c0 x + c1 d + c2 u
__global__ void k_scat2(const int* __restrict__ ldi, const float* __restrict__ ldv,
                        const int* __restrict__ lui, const float* __restrict__ luv,
                        float* __restrict__ ws)
{
    int gtid = blockIdx.x * 256 + threadIdx.x;    // 0 .. 2*E*8-1
    int b = gtid & 7;
    int e = gtid >> 3;
    const float* sc = ws + OFF_SC;
    const int* idx; const float* val; float c0, c1, c2;
    if (e < E) { idx = ldi; val = ldv; c0 = sc[3]; c1 = sc[4]; c2 = sc[5]; }
    else       { e -= E; idx = lui; val = luv; c0 = sc[6]; c1 = sc[7]; c2 = sc[8]; }
    int row = idx[e];
    int col = idx[E + e];
    float v = val[e];
    int ci = col * 8 + b;
    float h = c0 * ws[OFF_XT + ci] + c1 * ws[OFF_DD + ci] + c2 * ws[OFF_UU + ci];
    atomicAdd(&ws[OFF_Y + row * 8 + b], v * h);
}

// g[b,j] += sum_n yfull[n,b]*map_w[n,j], yfull = a0 x + a1 d + a2 u + Y
// 256 blocks x 32 rows each
__global__ void k_map(const float* __restrict__ map_w, float* __restrict__ ws)
{
    __shared__ float yf[32 * 8];
    int blk = blockIdx.x, tid = threadIdx.x;
    const float* sc = ws + OFF_SC;
    float* g = ws + OFF_G;
    int base = blk * 256;
    yf[tid] = sc[0] * ws[OFF_XT + base + tid] + sc[1] * ws[OFF_DD + base + tid]
            + sc[2] * ws[OFF_UU + base + tid] + ws[OFF_Y + base + tid];
    __syncthreads();
    float acc[8] = {0.f, 0.f, 0.f, 0.f, 0.f, 0.f, 0.f, 0.f};
    int nbase = blk * 32;
    #pragma unroll 4
    for (int r = 0; r < 32; r++) {
        float w = map_w[(nbase + r) * HID + tid];
        #pragma unroll
        for (int b = 0; b < 8; b++) acc[b] += yf[r * 8 + b] * w;
    }
    #pragma unroll
    for (int b = 0; b < 8; b++) atomicAdd(&g[b * HID + tid], acc[b]);
}

// fused output stage: s = silu(g @ o_w1 + o_b1); out = s @ o_w2 + o_b2
// 32 blocks x 1024 thr; block owns n-chunk of 256; single non-atomic writer.
__global__ __launch_bounds__(1024) void k_mlpout(
        const float* __restrict__ o_w1, const float* __restrict__ o_b1,
        const float* __restrict__ o_w2, const float* __restrict__ o_b2,
        const float* __restrict__ ws, float* __restrict__ out)
{
    __shared__ float gs[B * HID];        // 8KB
    __shared__ float part[4][B * HID];   // 32KB
    __shared__ float ssl[B * HID];       // 8KB
    const int blk = blockIdx.x, tid = threadIdx.x;
    gs[tid] = ws[OFF_G + tid];
    gs[1024 + tid] = ws[OFF_G + 1024 + tid];
    __syncthreads();
    // phase A: s partials, threads (j = tid&255, ic = tid>>8), depth 64
    {
        int j = tid & 255, ic = tid >> 8;
        float z[8] = {0.f, 0.f, 0.f, 0.f, 0.f, 0.f, 0.f, 0.f};
        #pragma unroll 4
        for (int i = ic * 64; i < ic * 64 + 64; i++) {
            float w = o_w1[i * HID + j];
            #pragma unroll
            for (int b = 0; b < 8; b++) z[b] += gs[b * HID + i] * w;
        }
        #pragma unroll
        for (int b = 0; b < 8; b++) part[ic][b * HID + j] = z[b];
    }
    __syncthreads();
    #pragma unroll
    for (int it = 0; it < 2; it++) {
        int P = it * 1024 + tid;          // = b*256 + j
        float zz = o_b1[P & 255] + part[0][P] + part[1][P] + part[2][P] + part[3][P];
        ssl[P] = zz / (1.f + expf(-zz));
    }
    __syncthreads();
    // phase B: out GEMV, threads (nl = tid&255, ic = tid>>8), depth 64
    {
        int nl = tid & 255, ic = tid >> 8;
        int n = blk * 256 + nl;
        float acc[8] = {0.f, 0.f, 0.f, 0.f, 0.f, 0.f, 0.f, 0.f};
        #pragma unroll 4
        for (int j = ic * 64; j < ic * 64 + 64; j++) {
            float w = o_w2[j * D + n];
            #pragma unroll
            for (int b = 0; b < 8; b++) acc[b] += ssl[b * HID + j] * w;
        }
        #pragma unroll
        for (int b = 0; b < 8; b++) part[ic][b * HID + nl] = acc[b];
    }
    __syncthreads();
    #pragma unroll
    for (int it = 0; it < 2; it++) {
        int P = it * 1024 + tid;          // = b*256 + nl
        int b = P >> 8, nl = P & 255;
        int n = blk * 256 + nl;
        out[b * D + n] = o_b2[n] + part[0][P] + part[1][P] + part[2][P] + part[3][P];
    }
}

extern "C" void kernel_launch(void* const* d_in, const int* in_sizes, int n_in,
                              void* d_out, int out_size, void* d_ws, size_t ws_size,
                              hipStream_t stream)
{
    const float* x     = (const float*)d_in[0];
    const float* t     = (const float*)d_in[1];
    const int*   ldi   = (const int*)  d_in[2];
    const float* ldv   = (const float*)d_in[3];
    const int*   lui   = (const int*)  d_in[4];
    const float* luv   = (const float*)d_in[5];
    const float* W1    = (const float*)d_in[6];
    const float* W2    = (const float*)d_in[7];
    const float* t_w1  = (const float*)d_in[8];
    const float* t_b1  = (const float*)d_in[9];
    const float* t_w2  = (const float*)d_in[10];
    const float* t_b2  = (const float*)d_in[11];
    const float* map_w = (const float*)d_in[12];
    const float* map_b = (const float*)d_in[13];
    const float* o_w1  = (const float*)d_in[14];
    const float* o_b1  = (const float*)d_in[15];
    const float* o_w2  = (const float*)d_in[16];
    const float* o_b2  = (const float*)d_in[17];
    float* out = (float*)d_out;
    float* ws  = (float*)d_ws;

    k_front<<<73, 1024, 0, stream>>>(x, t, W1, W2, t_w1, t_b1, t_w2, t_b2, map_b, ws);
    k_scat1<<<2 * E * 8 / 256, 256, 0, stream>>>(ldi, ldv, lui, luv, ws);
    k_scat2<<<2 * E * 8 / 256, 256, 0, stream>>>(ldi, ldv, lui, luv, ws);
    k_map<<<256, 256, 0, stream>>>(map_w, ws);
    k_mlpout<<<32, 1024, 0, stream>>>(o_w1, o_b1, o_w2, o_b2, ws, out);
}